// Round 7
// baseline (135.646 us; speedup 1.0000x reference)
//
#include <hip/hip_runtime.h>

// KLD RepPoints loss, R6: 2-deep software-pipelined gather.
// Model that fits R0-R5: limiter = line-level MLP x duty cycle (Little's
// law). R2's stride-72 float2 gather maximizes lines-in-flight per thread
// (~11-15); denser structures (R3 LDS staging, R4 float4 pairs) REDUCED
// line MLP and regressed. But every variant lets each wave alternate
// load-burst / zero-MLP compute (~400cyc of divs+log with nothing
// outstanding) -> duty ~55%, 3.4 TB/s read. R6: each thread owns exactly
// 2 elements; all 26 float2 loads issue unconditionally up front (clamp +
// select, no branches), compute of elem A waits only vmcnt(13), so elem
// B's lines stay in flight during A's compute -> duty -> ~1.

__device__ __forceinline__ float kld_elem(
    const float px[9], const float py[9],
    const float tx[4], const float ty[4])
{
    // ---- pred moments ----
    const float inv9 = 1.0f / 9.0f;
    float sx = 0.f, sy = 0.f;
    #pragma unroll
    for (int k = 0; k < 9; ++k) { sx += px[k]; sy += py[k]; }
    float mux = sx * inv9, muy = sy * inv9;
    float a = 0.f, b = 0.f, d = 0.f;   // p_var = [[a,b],[b,d]]
    #pragma unroll
    for (int k = 0; k < 9; ++k) {
        float xx = px[k] - mux, yy = py[k] - muy;
        a += xx * xx; b += xx * yy; d += yy * yy;
    }
    a = a * inv9 + 1e-6f;
    b = b * inv9;
    d = d * inv9 + 1e-6f;

    // ---- target box -> rotated Gaussian ----
    float tmux = (tx[0] + tx[1] + tx[2] + tx[3]) * 0.25f;
    float tmuy = (ty[0] + ty[1] + ty[2] + ty[3]) * 0.25f;
    float e1x = tx[1] - tx[0], e1y = ty[1] - ty[0];
    float e2x = tx[2] - tx[1], e2y = ty[2] - ty[1];
    float w = e1x * e1x + e1y * e1y;
    float h = e2x * e2x + e2y * e2y;
    float sw = sqrtf(w);
    float c = e1x / sw, s = e1y / sw;
    const float invLL = 1.0f / 36.0f;      // 1/(4*L*L), L=3
    float dw = w * invLL, dh = h * invLL;
    float tv00 = c * c * dw + s * s * dh;  // t_var = R diag(dw,dh) R^T
    float tv01 = c * s * (dw - dh);
    float tv11 = s * s * dw + c * c * dh;

    float t_det = tv00 * tv11 - tv01 * tv01;
    float p_det = a * d - b * b;
    float inv_tdet = 1.0f / t_det;

    float dx = mux - tmux, dy = muy - tmuy;
    float term1 = (dx * dx * tv11 - 2.0f * dx * dy * tv01 + dy * dy * tv00) * inv_tdet;
    float trace = (tv11 * a - 2.0f * tv01 * b + tv00 * d) * inv_tdet;
    float term2 = trace + logf(t_det / p_det);
    float kld = 0.5f * (term1 + term2) - 1.0f;
    float kl = fmaxf(kld, 1e-6f);
    return 1.0f - 1.0f / (2.0f + sqrtf(kl));
}

__global__ __launch_bounds__(256) void kld_partial_kernel(
    const float* __restrict__ pred,    // [n][9][2]
    const float* __restrict__ target,  // [n][4][2]
    float* __restrict__ ws,            // [gridDim.x] partial sums
    int n_total)
{
    const int tid0   = blockIdx.x * 256 + threadIdx.x;
    const int stride = gridDim.x * 256;
    const int nm1    = n_total - 1;

    // element indices, clamped (loads always in-bounds; invalid -> weight 0)
    int eA = tid0;            bool vA = (eA <= nm1); eA = vA ? eA : nm1;
    int eB = tid0 + stride;   bool vB = (eB <= nm1); eB = vB ? eB : nm1;

    const float2* pA = reinterpret_cast<const float2*>(pred)   + (size_t)eA * 9;
    const float2* tA = reinterpret_cast<const float2*>(target) + (size_t)eA * 4;
    const float2* pB = reinterpret_cast<const float2*>(pred)   + (size_t)eB * 9;
    const float2* tB = reinterpret_cast<const float2*>(target) + (size_t)eB * 4;

    // ---- issue ALL loads up front (26x float2), straight-line ----
    float2 a0 = pA[0], a1 = pA[1], a2 = pA[2], a3 = pA[3], a4 = pA[4],
           a5 = pA[5], a6 = pA[6], a7 = pA[7], a8 = pA[8];
    float2 qa0 = tA[0], qa1 = tA[1], qa2 = tA[2], qa3 = tA[3];
    float2 b0 = pB[0], b1 = pB[1], b2 = pB[2], b3 = pB[3], b4 = pB[4],
           b5 = pB[5], b6 = pB[6], b7 = pB[7], b8 = pB[8];
    float2 qb0 = tB[0], qb1 = tB[1], qb2 = tB[2], qb3 = tB[3];

    // ---- compute A (only waits on A's loads; B's stay in flight) ----
    float lossA, lossB;
    {
        float px[9] = {a0.x, a1.x, a2.x, a3.x, a4.x, a5.x, a6.x, a7.x, a8.x};
        float py[9] = {a0.y, a1.y, a2.y, a3.y, a4.y, a5.y, a6.y, a7.y, a8.y};
        float tx[4] = {qa0.x, qa1.x, qa2.x, qa3.x};
        float ty[4] = {qa0.y, qa1.y, qa2.y, qa3.y};
        lossA = kld_elem(px, py, tx, ty);
    }
    {
        float px[9] = {b0.x, b1.x, b2.x, b3.x, b4.x, b5.x, b6.x, b7.x, b8.x};
        float py[9] = {b0.y, b1.y, b2.y, b3.y, b4.y, b5.y, b6.y, b7.y, b8.y};
        float tx[4] = {qb0.x, qb1.x, qb2.x, qb3.x};
        float ty[4] = {qb0.y, qb1.y, qb2.y, qb3.y};
        lossB = kld_elem(px, py, tx, ty);
    }
    float loss = (vA ? lossA : 0.0f) + (vB ? lossB : 0.0f);

    // ---- reduction: wave64 shuffle -> LDS -> one plain store per block ----
    #pragma unroll
    for (int off = 32; off > 0; off >>= 1)
        loss += __shfl_down(loss, off, 64);

    __shared__ float sm[4];
    int lane = threadIdx.x & 63;
    int wid  = threadIdx.x >> 6;
    if (lane == 0) sm[wid] = loss;
    __syncthreads();
    if (threadIdx.x == 0)
        ws[blockIdx.x] = sm[0] + sm[1] + sm[2] + sm[3];
}

__global__ __launch_bounds__(256) void kld_final_kernel(
    const float* __restrict__ ws, float* __restrict__ out,
    int nblocks, float inv_n)
{
    float s = 0.0f;
    for (int i = threadIdx.x; i < nblocks; i += 256)
        s += ws[i];

    #pragma unroll
    for (int off = 32; off > 0; off >>= 1)
        s += __shfl_down(s, off, 64);

    __shared__ float sm[4];
    int lane = threadIdx.x & 63;
    int wid  = threadIdx.x >> 6;
    if (lane == 0) sm[wid] = s;
    __syncthreads();
    if (threadIdx.x == 0)
        out[0] = (sm[0] + sm[1] + sm[2] + sm[3]) * inv_n;
}

extern "C" void kernel_launch(void* const* d_in, const int* in_sizes, int n_in,
                              void* d_out, int out_size, void* d_ws, size_t ws_size,
                              hipStream_t stream) {
    const float* pred   = (const float*)d_in[0];
    const float* target = (const float*)d_in[1];
    float* out = (float*)d_out;
    float* ws  = (float*)d_ws;

    int n = in_sizes[0] / 18;           // N elements (pred is N*9*2 floats)
    int nblocks = (n + 511) / 512;      // 2 elements per thread
    if (nblocks < 1) nblocks = 1;

    kld_partial_kernel<<<nblocks, 256, 0, stream>>>(pred, target, ws, n);
    kld_final_kernel<<<1, 256, 0, stream>>>(ws, out, nblocks, 1.0f / (float)n);
}